// Round 11
// baseline (267.551 us; speedup 1.0000x reference)
//
#include <hip/hip_runtime.h>

// ---------------- constants ----------------
#define B_   16
#define T_   512
#define M_   8
#define S_   32
#define D_   256
#define H_   4
#define HD_  64
#define TM_  4096      // T*M
#define NKT  40        // M+S
#define NKS  4128      // T*M+S

typedef unsigned short u16;
typedef __attribute__((ext_vector_type(8))) short bf16x8;
typedef __attribute__((ext_vector_type(4))) float f32x4;

// ---------------- bf16 helpers ----------------
__device__ __forceinline__ u16 f2b(float f) {
    union { float f; unsigned u; } v; v.f = f;
    unsigned r = v.u + 0x7FFF + ((v.u >> 16) & 1);   // RNE
    return (u16)(r >> 16);
}
__device__ __forceinline__ float blo(unsigned u) {
    union { unsigned i; float f; } v; v.i = u << 16; return v.f;
}
__device__ __forceinline__ float bhi(unsigned u) {
    union { unsigned i; float f; } v; v.i = u & 0xFFFF0000u; return v.f;
}
__device__ __forceinline__ float b2f(u16 u) {
    union { unsigned i; float f; } v; v.i = ((unsigned)u) << 16; return v.f;
}
__device__ __forceinline__ unsigned pack2(float lo, float hi) {
    return (unsigned)f2b(lo) | ((unsigned)f2b(hi) << 16);
}
__device__ __forceinline__ uint4 cvt8(float4 a, float4 b) {
    uint4 r;
    r.x = pack2(a.x, a.y); r.y = pack2(a.z, a.w);
    r.z = pack2(b.x, b.y); r.w = pack2(b.z, b.w);
    return r;
}

#define GLL16(g, l) __builtin_amdgcn_global_load_lds( \
    (const __attribute__((address_space(1))) void*)(g), \
    (__attribute__((address_space(3))) void*)(l), 16, 0, 0)

// ---------------- weight pre-convert: f32 -> bf16 (RNE, bit-identical) --------
__global__ __launch_bounds__(256) void k_cvt_w(const float* __restrict__ W0,
                                               const float* __restrict__ W1,
                                               const float* __restrict__ W2,
                                               u16* __restrict__ dst)
{
    const int sel = blockIdx.y;
    const float* W = sel == 0 ? W0 : sel == 1 ? W1 : W2;
    u16* d = dst + sel * 65536;
    const int i0 = (blockIdx.x * 256 + threadIdx.x) * 8;
    const float4 a = *(const float4*)(W + i0);
    const float4 b = *(const float4*)(W + i0 + 4);
    *(uint4*)(d + i0) = cvt8(a, b);
}

// ---------------- GEMM body: Y[r][c] = X[r]·Wb[c] + bias[c] ----------------
// BM=128, BN=256 (whole N), BK=32, 8 K-steps, 4 waves. A is REG-STAGED with
// PREFETCH DISTANCE 2 (load for tile k+2 issued at step k; register loads are
// not drained by __syncthreads — only their use waits — so the prefetch spans
// two barriers, ~2 compute phases of latency budget). A LDS layout: padded
// stride 40 u16, conflict-free. B staged via global_load_lds with linear LDS
// dest + pre-swizzled global source (rule #21); reads use slot' = g^((c>>1)&3).
template<int XBF, int OUTF32>
__device__ __forceinline__ void gemm_body(const void* __restrict__ Xv,
                                          const u16* __restrict__ Wb,
                                          const float* __restrict__ bias,
                                          void* __restrict__ Yv,
                                          int bx, u16* smem)
{
    const int tid = threadIdx.x;
    const size_t r0 = (size_t)bx * 128;
    const int wave = tid >> 6, lane = tid & 63;
    const int c = lane & 15, g = lane >> 4;
    const int swzk = g ^ ((c >> 1) & 3);                 // B fragment k-slot
    const int swzl = (lane & 3) ^ ((lane >> 3) & 3);     // B staging src k-chunk
    u16* sA = smem;              // 2 x 5120 u16 (stride-40 padded)
    u16* sB = smem + 10240;      // 2 x 8192 u16
    const int ar = tid >> 1, ah = tid & 1;               // A staging coords

    f32x4 acc[8][4];
#pragma unroll
    for (int i = 0; i < 8; ++i)
#pragma unroll
        for (int j = 0; j < 4; ++j) acc[i][j] = (f32x4){0, 0, 0, 0};

    float4 fa[2][4];             // f32-A pending loads (ping-pong)
    uint4  ua[2][2];             // bf16-A pending loads

#define LOAD_A(k0, s)                                                           \
    if (XBF) {                                                                  \
        const u16* gA = (const u16*)Xv + (r0 + ar) * 256 + (k0) + ah * 16;      \
        ua[s][0] = *(const uint4*)gA; ua[s][1] = *(const uint4*)(gA + 8);       \
    } else {                                                                    \
        const float* gA = (const float*)Xv + (r0 + ar) * 256 + (k0) + ah * 16;  \
        fa[s][0] = *(const float4*)gA;       fa[s][1] = *(const float4*)(gA + 4); \
        fa[s][2] = *(const float4*)(gA + 8); fa[s][3] = *(const float4*)(gA + 12); \
    }
#define WRITE_A(bi, s)                                                          \
    {   u16* d = sA + (bi) * 5120 + ar * 40 + ah * 16;                          \
        if (XBF) { *(uint4*)d = ua[s][0]; *(uint4*)(d + 8) = ua[s][1]; }        \
        else { *(uint4*)d = cvt8(fa[s][0], fa[s][1]);                           \
               *(uint4*)(d + 8) = cvt8(fa[s][2], fa[s][3]); }                   \
    }
#define STAGE_B(k0, bi)                                                         \
    _Pragma("unroll")                                                           \
    for (int i = 0; i < 4; ++i) {                                               \
        const int row = i * 64 + wave * 16 + (lane >> 2);                       \
        GLL16(Wb + (size_t)row * 256 + (k0) + swzl * 8,                         \
              sB + (bi) * 8192 + (i * 256 + wave * 64) * 8);                    \
    }

    {   // prologue: tile 0 -> buf 0 (A via regs, B via GLL); issue A tile 1
        LOAD_A(0, 0)
        WRITE_A(0, 0)
        LOAD_A(32, 0)            // slot 0 free again after WRITE_A consumed it
        STAGE_B(0, 0)
    }

#pragma unroll
    for (int k = 0; k < 8; ++k) {
        const int cur = k & 1;
        __syncthreads();                 // drains B GLLs + A ds_writes of prior step
        if (k < 6) LOAD_A((k + 2) * 32, (k + 1) & 1)   // A prefetch, distance 2
        if (k < 7) STAGE_B((k + 1) * 32, cur ^ 1)
        bf16x8 a[8], b[4];
#pragma unroll
        for (int f = 0; f < 8; ++f)
            a[f] = *(const bf16x8*)(sA + cur * 5120 + (f * 16 + c) * 40 + g * 8);
#pragma unroll
        for (int f = 0; f < 4; ++f)
            b[f] = *(const bf16x8*)(sB + cur * 8192 + (wave * 64 + f * 16 + c) * 32 + swzk * 8);
#pragma unroll
        for (int rf = 0; rf < 8; ++rf)
#pragma unroll
            for (int cf = 0; cf < 4; ++cf)
                acc[rf][cf] = __builtin_amdgcn_mfma_f32_16x16x32_bf16(
                    a[rf], b[cf], acc[rf][cf], 0, 0, 0);
        if (k < 7) WRITE_A(cur ^ 1, k & 1)   // waits load issued at step k-1
    }
#undef LOAD_A
#undef WRITE_A
#undef STAGE_B

    // C/D mapping (bit-verified rounds 2/3): col=lane&15, row=(lane>>4)*4+reg
    const int orow = g * 4, ocol = c;
    if (OUTF32) {
#pragma unroll
        for (int cf = 0; cf < 4; ++cf) {
            const int col = wave * 64 + cf * 16 + ocol;
            const float bv = bias[col];
#pragma unroll
            for (int rf = 0; rf < 8; ++rf)
#pragma unroll
                for (int r = 0; r < 4; ++r)
                    ((float*)Yv)[(r0 + rf * 16 + orow + r) * 256 + col] =
                        acc[rf][cf][r] + bv;
        }
    } else {
        // bf16 out: two-phase LDS transpose (stride 264) -> coalesced dwordx4
#pragma unroll
        for (int hh = 0; hh < 2; ++hh) {
            __syncthreads();
#pragma unroll
            for (int cf = 0; cf < 4; ++cf) {
                const int col = wave * 64 + cf * 16 + ocol;
                const float bv = bias[col];
#pragma unroll
                for (int rf4 = 0; rf4 < 4; ++rf4)
#pragma unroll
                    for (int r = 0; r < 4; ++r)
                        smem[(rf4 * 16 + orow + r) * 264 + col] =
                            f2b(acc[hh * 4 + rf4][cf][r] + bv);
            }
            __syncthreads();
#pragma unroll
            for (int i = 0; i < 8; ++i) {
                const int s = i * 256 + tid;
                const int row = s >> 5, seg = s & 31;
                *(uint4*)((u16*)Yv + (r0 + hh * 64 + row) * 256 + seg * 8) =
                    *(const uint4*)(smem + row * 264 + seg * 8);
            }
        }
    }
}

template<int XBF, int OUTF32>
__global__ __launch_bounds__(256, 2) void k_gemm_m(const void* __restrict__ Xv,
                                                   const u16* __restrict__ Wb,
                                                   const float* __restrict__ bias,
                                                   void* __restrict__ Yv)
{
    __shared__ __align__(16) u16 smem[26624];
    gemm_body<XBF, OUTF32>(Xv, Wb, bias, Yv, blockIdx.x, smem);
}

// Fused 3-projection GEMM: blockIdx.y selects {q,k,v}; Wb = pre-converted bf16.
__global__ __launch_bounds__(256, 2) void k_gemm_qkv(
    const float* __restrict__ X0, const float* __restrict__ X1, const float* __restrict__ X2,
    const u16* __restrict__ Wb,
    const float* __restrict__ b0, const float* __restrict__ b1, const float* __restrict__ b2,
    u16* __restrict__ Y0, u16* __restrict__ Y1, u16* __restrict__ Y2)
{
    __shared__ __align__(16) u16 smem[26624];
    const int sel = blockIdx.y;
    const float* X = sel == 0 ? X0 : sel == 1 ? X1 : X2;
    const float* bb = sel == 0 ? b0 : sel == 1 ? b1 : b2;
    u16* Y = sel == 0 ? Y0 : sel == 1 ? Y1 : Y2;
    gemm_body<0, 0>(X, Wb + sel * 65536, bb, Y, blockIdx.x, smem);
}

// ---------------- temporal attention (MFMA): one block per (t-pair, b) --------
__global__ __launch_bounds__(256) void k_attn_t(
    const u16* __restrict__ Qt, const u16* __restrict__ Kt, const u16* __restrict__ Vt,
    const u16* __restrict__ Ks, const u16* __restrict__ Vs,
    const int* __restrict__ maskT, const int* __restrict__ maskS,
    float* __restrict__ tw, u16* __restrict__ qkvt)
{
    const int tp = blockIdx.x, b = blockIdx.y;
    const int t0 = tp * 2;
    __shared__ __align__(16) u16 sQ [4 * 2 * 16 * 32];   // [h][ks][row16][32]
    __shared__ __align__(16) u16 sKT[4 * 2 * 16 * 32];
    __shared__ __align__(16) u16 sKS[4 * 2 * 32 * 32];
    __shared__ __align__(16) u16 sVT[4 * 64 * 72];       // [h][d64][key72], keys48-63=0
    __shared__ __align__(16) u16 sP [4 * 16 * 72];
    __shared__ int smT[2][8];
    __shared__ int smS[32];
    const int tid = threadIdx.x;

#pragma unroll
    for (int i = 0; i < 2; ++i) {
        const int fl = tid + i * 256;
        const int r = fl >> 5, c32 = fl & 31;
        const int h = c32 >> 3, ks = (c32 >> 2) & 1, seg = c32 & 3;
        const size_t src = (((size_t)b * T_ + t0 + (r >> 3)) * 8 + (r & 7)) * 256 + c32 * 8;
        const int dst = h * 1024 + ks * 512 + r * 32 + seg * 8;
        *(uint4*)(sQ  + dst) = *(const uint4*)(Qt + src);
        *(uint4*)(sKT + dst) = *(const uint4*)(Kt + src);
    }
#pragma unroll
    for (int i = 0; i < 4; ++i) {
        const int fl = tid + i * 256;
        const int r = fl >> 5, c32 = fl & 31;
        const int h = c32 >> 3, ks = (c32 >> 2) & 1, seg = c32 & 3;
        *(uint4*)(sKS + h * 2048 + ks * 1024 + r * 32 + seg * 8) =
            *(const uint4*)(Ks + ((size_t)b * S_ + r) * 256 + c32 * 8);
    }
    {
        const int key = tid & 63, dg = tid >> 6;
        const u16* vrow = nullptr;
        if (key < 16)      vrow = Vt + (((size_t)b * T_ + t0 + (key >> 3)) * 8 + (key & 7)) * 256;
        else if (key < 48) vrow = Vs + ((size_t)b * S_ + (key - 16)) * 256;
#pragma unroll
        for (int i = 0; i < 8; ++i) {
            const int dseg = dg * 8 + i;
            uint4 v = {0, 0, 0, 0};
            if (vrow) v = *(const uint4*)(vrow + dseg * 8);
            const int h = dseg >> 3, dl0 = (dseg & 7) * 8;
            const u16* pv = (const u16*)&v;
#pragma unroll
            for (int j = 0; j < 8; ++j)
                sVT[h * 4608 + (dl0 + j) * 72 + key] = pv[j];
        }
    }
    if (tid < 16) smT[tid >> 3][tid & 7] =
        maskT[((size_t)b * T_ + t0 + (tid >> 3)) * 8 + (tid & 7)];
    if (tid < 32) smS[tid] = maskS[b * S_ + tid];
    __syncthreads();

    const int h = tid >> 6, lane = tid & 63;
    const int c = lane & 15, g = lane >> 4, th = g >> 1;

    f32x4 at = {0,0,0,0}, as0 = {0,0,0,0}, as1 = {0,0,0,0};
#pragma unroll
    for (int ks = 0; ks < 2; ++ks) {
        bf16x8 aq = *(const bf16x8*)(sQ  + h * 1024 + ks * 512 + c * 32 + g * 8);
        bf16x8 bt = *(const bf16x8*)(sKT + h * 1024 + ks * 512 + c * 32 + g * 8);
        bf16x8 b0 = *(const bf16x8*)(sKS + h * 2048 + ks * 1024 + c * 32 + g * 8);
        bf16x8 b1 = *(const bf16x8*)(sKS + h * 2048 + ks * 1024 + 512 + c * 32 + g * 8);
        at  = __builtin_amdgcn_mfma_f32_16x16x32_bf16(aq, bt, at, 0, 0, 0);
        as0 = __builtin_amdgcn_mfma_f32_16x16x32_bf16(aq, b0, as0, 0, 0, 0);
        as1 = __builtin_amdgcn_mfma_f32_16x16x32_bf16(aq, b1, as1, 0, 0, 0);
    }

    const int vt = ((c >> 3) == th) ? smT[th][c & 7] : 0;
    const int v0 = smS[c], v1 = smS[16 + c];
    float st[4], s0[4], s1[4], mx[4];
#pragma unroll
    for (int r = 0; r < 4; ++r) {
        st[r] = vt ? at[r]  * 0.125f : -1e30f;
        s0[r] = v0 ? as0[r] * 0.125f : -1e30f;
        s1[r] = v1 ? as1[r] * 0.125f : -1e30f;
        mx[r] = fmaxf(fmaxf(st[r], s0[r]), s1[r]);
    }
#pragma unroll
    for (int o = 1; o < 16; o <<= 1)
#pragma unroll
        for (int r = 0; r < 4; ++r) mx[r] = fmaxf(mx[r], __shfl_xor(mx[r], o));
    float pt[4], p0[4], p1[4], sum[4];
#pragma unroll
    for (int r = 0; r < 4; ++r) {
        pt[r] = __expf(st[r] - mx[r]);
        p0[r] = __expf(s0[r] - mx[r]);
        p1[r] = __expf(s1[r] - mx[r]);
        sum[r] = pt[r] + p0[r] + p1[r];
    }
#pragma unroll
    for (int o = 1; o < 16; o <<= 1)
#pragma unroll
        for (int r = 0; r < 4; ++r) sum[r] += __shfl_xor(sum[r], o);
#pragma unroll
    for (int r = 0; r < 4; ++r) {
        const float inv = 1.0f / sum[r];
        pt[r] *= inv; p0[r] *= inv; p1[r] *= inv;
    }

#pragma unroll
    for (int r = 0; r < 4; ++r) {
        const int row = g * 4 + r;
        const int tt = t0 + (row >> 3), m = row & 7;
        float* twp = tw + ((((size_t)b * H_ + h) * T_ + tt) * 8 + m) * NKT;
        if ((c >> 3) == th) twp[c & 7] = pt[r];
        twp[8 + c]  = p0[r];
        twp[24 + c] = p1[r];
        u16* sp = sP + h * 1152 + row * 72;
        sp[c]      = f2b(pt[r]);
        sp[16 + c] = f2b(p0[r]);
        sp[32 + c] = f2b(p1[r]);
        sp[48 + c] = 0;
    }

    f32x4 o4[4] = {{0,0,0,0}, {0,0,0,0}, {0,0,0,0}, {0,0,0,0}};
#pragma unroll
    for (int ks = 0; ks < 2; ++ks) {
        bf16x8 pa = *(const bf16x8*)(sP + h * 1152 + c * 72 + ks * 32 + g * 8);
#pragma unroll
        for (int dt = 0; dt < 4; ++dt) {
            bf16x8 pb = *(const bf16x8*)(sVT + h * 4608 + (dt * 16 + c) * 72 + ks * 32 + g * 8);
            o4[dt] = __builtin_amdgcn_mfma_f32_16x16x32_bf16(pa, pb, o4[dt], 0, 0, 0);
        }
    }
#pragma unroll
    for (int dt = 0; dt < 4; ++dt)
#pragma unroll
        for (int r = 0; r < 4; ++r) {
            const int row = g * 4 + r;
            const int tt = t0 + (row >> 3), m = row & 7;
            qkvt[(((size_t)b * T_ + tt) * 8 + m) * 256 + h * 64 + dt * 16 + c] = f2b(o4[dt][r]);
        }
}

// ---------------- static branch: raw masked scores (MFMA) ----------------
__global__ __launch_bounds__(256) void k_attn_s_scores(
    const u16* __restrict__ Qs, const u16* __restrict__ Kt, const u16* __restrict__ Ks,
    const int* __restrict__ maskT, const int* __restrict__ maskS,
    float* __restrict__ raw)
{
    const int ch = blockIdx.x, h = blockIdx.y, b = blockIdx.z;
    const int nk = (ch < 32) ? 128 : 32;
    const int k0 = ch * 128;
    __shared__ __align__(16) u16 sQ[2 * 32 * 32];
    __shared__ __align__(16) u16 sK[2 * 128 * 32];
    __shared__ int sM[128];
    const int tid = threadIdx.x;

    {   const int q = tid >> 3, c8 = tid & 7;
        const int ks = c8 >> 2, seg = c8 & 3;
        *(uint4*)(sQ + ks * 1024 + q * 32 + seg * 8) =
            *(const uint4*)(Qs + ((size_t)b * S_ + q) * 256 + h * 64 + c8 * 8);
    }
#pragma unroll
    for (int i = 0; i < 4; ++i) {
        const int fl = tid + i * 256;
        const int key = fl >> 3, c8 = fl & 7;
        const int ks = c8 >> 2, seg = c8 & 3;
        if (key < nk) {
            const u16* src = (ch < 32)
                ? (Kt + ((size_t)b * TM_ + k0 + key) * 256 + h * 64 + c8 * 8)
                : (Ks + ((size_t)b * S_  +      key) * 256 + h * 64 + c8 * 8);
            *(uint4*)(sK + ks * 4096 + key * 32 + seg * 8) = *(const uint4*)src;
        }
    }
    if (tid < nk) sM[tid] = (ch < 32) ? maskT[(size_t)b * TM_ + k0 + tid]
                                      : maskS[b * S_ + tid];
    __syncthreads();

    const int w = tid >> 6, lane = tid & 63;
    if (w * 32 >= nk) return;
    const int c = lane & 15, g = lane >> 4;

    f32x4 acc[2][2] = {{{0,0,0,0}, {0,0,0,0}}, {{0,0,0,0}, {0,0,0,0}}};
#pragma unroll
    for (int ks = 0; ks < 2; ++ks) {
        bf16x8 a0 = *(const bf16x8*)(sQ + ks * 1024 +        c * 32 + g * 8);
        bf16x8 a1 = *(const bf16x8*)(sQ + ks * 1024 + 512 +  c * 32 + g * 8);
        bf16x8 b0 = *(const bf16x8*)(sK + ks * 4096 + (w * 32 +      c) * 32 + g * 8);
        bf16x8 b1 = *(const bf16x8*)(sK + ks * 4096 + (w * 32 + 16 + c) * 32 + g * 8);
        acc[0][0] = __builtin_amdgcn_mfma_f32_16x16x32_bf16(a0, b0, acc[0][0], 0, 0, 0);
        acc[0][1] = __builtin_amdgcn_mfma_f32_16x16x32_bf16(a0, b1, acc[0][1], 0, 0, 0);
        acc[1][0] = __builtin_amdgcn_mfma_f32_16x16x32_bf16(a1, b0, acc[1][0], 0, 0, 0);
        acc[1][1] = __builtin_amdgcn_mfma_f32_16x16x32_bf16(a1, b1, acc[1][1], 0, 0, 0);
    }
#pragma unroll
    for (int rt = 0; rt < 2; ++rt)
#pragma unroll
        for (int ct = 0; ct < 2; ++ct) {
            const int kl = w * 32 + ct * 16 + c;
            const float madd = sM[kl] ? 0.f : -1e30f;
#pragma unroll
            for (int r = 0; r < 4; ++r) {
                const int q = rt * 16 + g * 4 + r;
                raw[(((size_t)b * H_ + h) * S_ + q) * NKS + k0 + kl] =
                    acc[rt][ct][r] * 0.125f + madd;
            }
        }
}

// ---------------- static branch: row softmax (reads raw, writes sw only) -------
__global__ __launch_bounds__(256) void k_attn_s_softmax(
    const float* __restrict__ raw, float* __restrict__ sw)
{
    const int q = blockIdx.x, h = blockIdx.y, b = blockIdx.z;
    __shared__ float sRow[NKS];
    __shared__ float red[8];
    const int tid = threadIdx.x;
    const size_t base = (((size_t)b * H_ + h) * S_ + q) * NKS;

    float mx = -1e30f;
    for (int i = tid; i < NKS; i += 256) {
        const float v = raw[base + i];
        sRow[i] = v;
        mx = fmaxf(mx, v);
    }
    for (int o = 32; o; o >>= 1) mx = fmaxf(mx, __shfl_xor(mx, o));
    if ((tid & 63) == 0) red[tid >> 6] = mx;
    __syncthreads();
    mx = fmaxf(fmaxf(red[0], red[1]), fmaxf(red[2], red[3]));

    float sum = 0.f;
    for (int i = tid; i < NKS; i += 256) {
        const float e = __expf(sRow[i] - mx);
        sRow[i] = e;
        sum += e;
    }
    for (int o = 32; o; o >>= 1) sum += __shfl_xor(sum, o);
    if ((tid & 63) == 0) red[4 + (tid >> 6)] = sum;
    __syncthreads();
    sum = (red[4] + red[5]) + (red[6] + red[7]);
    const float inv = 1.0f / sum;

    for (int i = tid; i < NKS; i += 256)
        sw[base + i] = sRow[i] * inv;           // single copy; pv reads sw
}

// ---------------- static branch: split-K PV partials (reads sw) ----------------
__global__ __launch_bounds__(256) void k_attn_s_pv_part(
    const float* __restrict__ w, const u16* __restrict__ Vt, const u16* __restrict__ Vs,
    float* __restrict__ part)
{
    const int ch = blockIdx.x, h = blockIdx.y, b = blockIdx.z;
    const int nk = (ch < 32) ? 128 : 32;
    const int k0 = ch * 128;
    __shared__ float sW[32][132];
    __shared__ __align__(16) u16 sV[128 * 64];
    const int tid = threadIdx.x;

#pragma unroll
    for (int i = 0; i < 4; ++i) {
        const int fl = tid + i * 256;
        const int q = fl >> 5, k4 = fl & 31;
        if (k4 * 4 < nk)
            *(float4*)&sW[q][k4 * 4] =
                *(const float4*)(w + (((size_t)b * H_ + h) * S_ + q) * NKS + k0 + k4 * 4);
    }
#pragma unroll
    for (int i = 0; i < 4; ++i) {
        const int fl = tid + i * 256;
        const int key = fl >> 3, pp = fl & 7;
        if (key < nk) {
            const u16* src = (ch < 32)
                ? (Vt + ((size_t)b * TM_ + k0 + key) * D_ + h * HD_ + pp * 8)
                : (Vs + ((size_t)b * S_  +      key) * D_ + h * HD_ + pp * 8);
            ((uint4*)sV)[fl] = *(const uint4*)src;
        }
    }
    __syncthreads();

    const int d = tid & 63, qg = tid >> 6;
    float acc[8] = {0,0,0,0,0,0,0,0};
    for (int kk = 0; kk < nk; kk += 4) {
        const float v0 = b2f(sV[(kk + 0) * 64 + d]);
        const float v1 = b2f(sV[(kk + 1) * 64 + d]);
        const float v2 = b2f(sV[(kk + 2) * 64 + d]);
        const float v3 = b2f(sV[(kk + 3) * 64 + d]);
#pragma unroll
        for (int j = 0; j < 8; ++j) {
            const float4 wv = *(const float4*)&sW[qg * 8 + j][kk];
            acc[j] += wv.x * v0 + wv.y * v1 + wv.z * v2 + wv.w * v3;
        }
    }

    float* pb = part + (((size_t)ch * B_ + b) * H_ + h) * 2048;
#pragma unroll
    for (int j = 0; j < 8; ++j)
        pb[(qg * 8 + j) * 64 + d] = acc[j];
}

// ---------------- static branch: PV reduce ----------------
__global__ __launch_bounds__(256) void k_attn_s_pv_red(
    const float* __restrict__ part, u16* __restrict__ qkvs)
{
    const int h = blockIdx.x, b = blockIdx.y;
    const int tid = threadIdx.x;
    for (int i = tid; i < 2048; i += 256) {
        float s = 0.f;
#pragma unroll
        for (int c = 0; c < 33; ++c)
            s += part[(((size_t)c * B_ + b) * H_ + h) * 2048 + i];
        const int q = i >> 6, d = i & 63;
        qkvs[((size_t)b * S_ + q) * D_ + h * HD_ + d] = f2b(s);
    }
}

// ---------------- launch ----------------
extern "C" void kernel_launch(void* const* d_in, const int* in_sizes, int n_in,
                              void* d_out, int out_size, void* d_ws, size_t ws_size,
                              hipStream_t stream)
{
    const float* q_t = (const float*)d_in[0];
    const float* q_s = (const float*)d_in[1];
    const float* k_t = (const float*)d_in[2];
    const float* v_t = (const float*)d_in[3];
    const float* k_s = (const float*)d_in[4];
    const float* v_s = (const float*)d_in[5];
    const float* q_w = (const float*)d_in[6];
    const float* q_b = (const float*)d_in[7];
    const float* k_w = (const float*)d_in[8];
    const float* k_b = (const float*)d_in[9];
    const float* v_w = (const float*)d_in[10];
    const float* v_b = (const float*)d_in[11];
    const float* o_w = (const float*)d_in[12];
    const float* o_b = (const float*)d_in[13];
    const int* maskT = (const int*)d_in[14];
    // d_in[15] = mask_fcst: unused by the reference
    const int* maskS = (const int*)d_in[16];
    float* out = (float*)d_out;

    char* ws = (char*)d_ws;
    u16*   Kt   = (u16*)(ws + 0);
    u16*   Vt   = (u16*)(ws + 33554432);
    u16*   QKVt = (u16*)(ws + 67108864);
    float* part = (float*)(ws + 67108864);   // aliases QKVt (dead after out_t GEMM)
    u16*   Wqkv = (u16*)(ws + 67108864);     // aliases QKVt: live only during qkv GEMMs
    u16*   Qs   = (u16*)(ws + 100663296);
    u16*   Ks   = (u16*)(ws + 100925440);
    u16*   Vs   = (u16*)(ws + 101187584);
    u16*   QKVs = (u16*)(ws + 101449728);
    u16*   Qt   = (u16*)(ws + 101711872);
    float* raw  = (float*)(ws + 101711872);  // aliases Qt (dead before scores run)
    u16*   Wo   = (u16*)(ws + 101711872);    // aliases raw head: converted twice (see order)
    if (ws_size < 135528448) return;         // required workspace

    float* out_t = out;                 // [B,T,M,D]
    float* out_s = out + 16777216;      // [B,S,D]
    float* tw    = out + 16908288;      // [B,H,T,M,40]
    float* sw    = out + 27394048;      // [B,H,S,4128]

    const dim3 blk(256);
    // W pre-convert (q,k,v) into dead QKVt region
    k_cvt_w<<<dim3(32, 3), blk, 0, stream>>>(q_w, k_w, v_w, Wqkv);

    k_gemm_qkv<<<dim3(512, 3), blk, 0, stream>>>(q_t, k_t, v_t, Wqkv,
                                                 q_b, k_b, v_b, Qt, Kt, Vt);
    k_gemm_qkv<<<dim3(4, 3),   blk, 0, stream>>>(q_s, k_s, v_s, Wqkv,
                                                 q_b, k_b, v_b, Qs, Ks, Vs);

    k_attn_t<<<dim3(256, 16), blk, 0, stream>>>(Qt, Kt, Vt, Ks, Vs, maskT, maskS, tw, QKVt);

    // o_w convert #1 into raw region (Qt dead after attn_t; scores clobbers it later)
    k_cvt_w<<<dim3(32, 1), blk, 0, stream>>>(o_w, o_w, o_w, Wo);
    // out_t projection: frees QKVt so PV partials can alias it.
    k_gemm_m<1,1><<<dim3(512), blk, 0, stream>>>(QKVt, Wo, o_b, out_t);

    k_attn_s_scores<<<dim3(33, 4, 16), blk, 0, stream>>>(Qs, Kt, Ks, maskT, maskS, raw);
    k_attn_s_softmax<<<dim3(32, 4, 16), blk, 0, stream>>>(raw, sw);
    // o_w convert #2 (raw dead after softmax; pv reads sw)
    k_cvt_w<<<dim3(32, 1), blk, 0, stream>>>(o_w, o_w, o_w, Wo);
    k_attn_s_pv_part<<<dim3(33, 4, 16), blk, 0, stream>>>(sw, Vt, Vs, part);
    k_attn_s_pv_red<<<dim3(4, 16), blk, 0, stream>>>(part, QKVs);

    k_gemm_m<1,1><<<dim3(4),   blk, 0, stream>>>(QKVs, Wo, o_b, out_s);
}

// Round 12
// 261.859 us; speedup vs baseline: 1.0217x; 1.0217x over previous
//
#include <hip/hip_runtime.h>

// ---------------- constants ----------------
#define B_   16
#define T_   512
#define M_   8
#define S_   32
#define D_   256
#define H_   4
#define HD_  64
#define TM_  4096      // T*M
#define NKT  40        // M+S
#define NKS  4128      // T*M+S

typedef unsigned short u16;
typedef __attribute__((ext_vector_type(8))) short bf16x8;
typedef __attribute__((ext_vector_type(4))) float f32x4;

// ---------------- bf16 helpers ----------------
__device__ __forceinline__ u16 f2b(float f) {
    union { float f; unsigned u; } v; v.f = f;
    unsigned r = v.u + 0x7FFF + ((v.u >> 16) & 1);   // RNE
    return (u16)(r >> 16);
}
__device__ __forceinline__ float blo(unsigned u) {
    union { unsigned i; float f; } v; v.i = u << 16; return v.f;
}
__device__ __forceinline__ float bhi(unsigned u) {
    union { unsigned i; float f; } v; v.i = u & 0xFFFF0000u; return v.f;
}
__device__ __forceinline__ float b2f(u16 u) {
    union { unsigned i; float f; } v; v.i = ((unsigned)u) << 16; return v.f;
}
__device__ __forceinline__ unsigned pack2(float lo, float hi) {
    return (unsigned)f2b(lo) | ((unsigned)f2b(hi) << 16);
}
__device__ __forceinline__ uint4 cvt8(float4 a, float4 b) {
    uint4 r;
    r.x = pack2(a.x, a.y); r.y = pack2(a.z, a.w);
    r.z = pack2(b.x, b.y); r.w = pack2(b.z, b.w);
    return r;
}

#define GLL16(g, l) __builtin_amdgcn_global_load_lds( \
    (const __attribute__((address_space(1))) void*)(g), \
    (__attribute__((address_space(3))) void*)(l), 16, 0, 0)

// ---------------- weight pre-convert: f32 -> bf16 (RNE, bit-identical) --------
__global__ __launch_bounds__(256) void k_cvt_w(const float* __restrict__ W0,
                                               const float* __restrict__ W1,
                                               const float* __restrict__ W2,
                                               u16* __restrict__ dst)
{
    const int sel = blockIdx.y;
    const float* W = sel == 0 ? W0 : sel == 1 ? W1 : W2;
    u16* d = dst + sel * 65536;
    const int i0 = (blockIdx.x * 256 + threadIdx.x) * 8;
    const float4 a = *(const float4*)(W + i0);
    const float4 b = *(const float4*)(W + i0 + 4);
    *(uint4*)(d + i0) = cvt8(a, b);
}

// ---------------- GEMM body: Y[r][c] = X[r]·Wb[c] + bias[c] ----------------
// BM=128, BN=256, BK=32, 8 K-steps, 4 waves. T4 schedule: raw s_barrier with
// COUNTED vmcnt — A register-prefetch (distance 2) genuinely survives the
// barrier (old __syncthreads drained vmcnt(0), defeating all prior pipelining).
// Per step (wave program order, pinned by sched_barrier fences):
//   GLL B(k+1)x4 | A-load(k+2)x4 | ds_read+MFMA | WRITE_A(k+1) [auto-waits
//   its regs, FIFO-retires A(k+1)] | s_waitcnt vmcnt(4) lgkmcnt(0) [retires
//   GLL(k+1), KEEPS A(k+2) in flight] | s_barrier.
template<int XBF, int OUTF32>
__device__ __forceinline__ void gemm_body(const void* __restrict__ Xv,
                                          const u16* __restrict__ Wb,
                                          const float* __restrict__ bias,
                                          void* __restrict__ Yv,
                                          int bx, u16* smem)
{
    const int tid = threadIdx.x;
    const size_t r0 = (size_t)bx * 128;
    const int wave = tid >> 6, lane = tid & 63;
    const int c = lane & 15, g = lane >> 4;
    const int swzk = g ^ ((c >> 1) & 3);                 // B fragment k-slot
    const int swzl = (lane & 3) ^ ((lane >> 3) & 3);     // B staging src k-chunk
    u16* sA = smem;              // 2 x 5120 u16 (stride-40 padded)
    u16* sB = smem + 10240;      // 2 x 8192 u16
    const int ar = tid >> 1, ah = tid & 1;               // A staging coords

    f32x4 acc[8][4];
#pragma unroll
    for (int i = 0; i < 8; ++i)
#pragma unroll
        for (int j = 0; j < 4; ++j) acc[i][j] = (f32x4){0, 0, 0, 0};

    float4 fa[2][4];             // f32-A pending loads (ping-pong)
    uint4  ua[2][2];             // bf16-A pending loads

#define LOAD_A(k0, s)                                                           \
    if (XBF) {                                                                  \
        const u16* gA = (const u16*)Xv + (r0 + ar) * 256 + (k0) + ah * 16;      \
        ua[s][0] = *(const uint4*)gA; ua[s][1] = *(const uint4*)(gA + 8);       \
    } else {                                                                    \
        const float* gA = (const float*)Xv + (r0 + ar) * 256 + (k0) + ah * 16;  \
        fa[s][0] = *(const float4*)gA;       fa[s][1] = *(const float4*)(gA + 4); \
        fa[s][2] = *(const float4*)(gA + 8); fa[s][3] = *(const float4*)(gA + 12); \
    }
#define WRITE_A(bi, s)                                                          \
    {   u16* d = sA + (bi) * 5120 + ar * 40 + ah * 16;                          \
        if (XBF) { *(uint4*)d = ua[s][0]; *(uint4*)(d + 8) = ua[s][1]; }        \
        else { *(uint4*)d = cvt8(fa[s][0], fa[s][1]);                           \
               *(uint4*)(d + 8) = cvt8(fa[s][2], fa[s][3]); }                   \
    }
#define STAGE_B(k0, bi)                                                         \
    _Pragma("unroll")                                                           \
    for (int i = 0; i < 4; ++i) {                                               \
        const int row = i * 64 + wave * 16 + (lane >> 2);                       \
        GLL16(Wb + (size_t)row * 256 + (k0) + swzl * 8,                         \
              sB + (bi) * 8192 + (i * 256 + wave * 64) * 8);                    \
    }

    {   // prologue: B(0) via GLL; A(0) regs -> LDS; A(1) in flight across barrier
        STAGE_B(0, 0)
        LOAD_A(0, 0)
        WRITE_A(0, 0)            // auto-waits A(0) regs (also retires GLL(0))
        LOAD_A(32, 1)            // A(1) outstanding across the barrier
        asm volatile("s_waitcnt lgkmcnt(0)" ::: "memory");
        __builtin_amdgcn_s_barrier();
        __builtin_amdgcn_sched_barrier(0);
    }

#pragma unroll
    for (int k = 0; k < 8; ++k) {
        const int cur = k & 1;
        if (k < 7) { STAGE_B((k + 1) * 32, cur ^ 1) }    // oldest this step
        __builtin_amdgcn_sched_barrier(0);               // pin GLL before A-loads
        if (k < 6) { LOAD_A((k + 2) * 32, k & 1) }       // newest: spans barrier
        __builtin_amdgcn_sched_barrier(0);

        bf16x8 a[8], b[4];
#pragma unroll
        for (int f = 0; f < 8; ++f)
            a[f] = *(const bf16x8*)(sA + cur * 5120 + (f * 16 + c) * 40 + g * 8);
#pragma unroll
        for (int f = 0; f < 4; ++f)
            b[f] = *(const bf16x8*)(sB + cur * 8192 + (wave * 64 + f * 16 + c) * 32 + swzk * 8);
#pragma unroll
        for (int rf = 0; rf < 8; ++rf)
#pragma unroll
            for (int cf = 0; cf < 4; ++cf)
                acc[rf][cf] = __builtin_amdgcn_mfma_f32_16x16x32_bf16(
                    a[rf], b[cf], acc[rf][cf], 0, 0, 0);
        if (k < 7) WRITE_A(cur ^ 1, (k + 1) & 1)         // waits A(k+1) regs only

        if (k <= 5) {            // retire GLL(k+1); KEEP A(k+2) in flight
            if (XBF) asm volatile("s_waitcnt vmcnt(2) lgkmcnt(0)" ::: "memory");
            else     asm volatile("s_waitcnt vmcnt(4) lgkmcnt(0)" ::: "memory");
            __builtin_amdgcn_s_barrier();
            __builtin_amdgcn_sched_barrier(0);
        } else if (k == 6) {     // last staged tile: drain all
            asm volatile("s_waitcnt vmcnt(0) lgkmcnt(0)" ::: "memory");
            __builtin_amdgcn_s_barrier();
            __builtin_amdgcn_sched_barrier(0);
        }
    }
#undef LOAD_A
#undef WRITE_A
#undef STAGE_B

    // C/D mapping (bit-verified rounds 2/3): col=lane&15, row=(lane>>4)*4+reg
    const int orow = g * 4, ocol = c;
    if (OUTF32) {
#pragma unroll
        for (int cf = 0; cf < 4; ++cf) {
            const int col = wave * 64 + cf * 16 + ocol;
            const float bv = bias[col];
#pragma unroll
            for (int rf = 0; rf < 8; ++rf)
#pragma unroll
                for (int r = 0; r < 4; ++r)
                    ((float*)Yv)[(r0 + rf * 16 + orow + r) * 256 + col] =
                        acc[rf][cf][r] + bv;
        }
    } else {
        // bf16 out: two-phase LDS transpose (stride 264) -> coalesced dwordx4
#pragma unroll
        for (int hh = 0; hh < 2; ++hh) {
            __syncthreads();
#pragma unroll
            for (int cf = 0; cf < 4; ++cf) {
                const int col = wave * 64 + cf * 16 + ocol;
                const float bv = bias[col];
#pragma unroll
                for (int rf4 = 0; rf4 < 4; ++rf4)
#pragma unroll
                    for (int r = 0; r < 4; ++r)
                        smem[(rf4 * 16 + orow + r) * 264 + col] =
                            f2b(acc[hh * 4 + rf4][cf][r] + bv);
            }
            __syncthreads();
#pragma unroll
            for (int i = 0; i < 8; ++i) {
                const int s = i * 256 + tid;
                const int row = s >> 5, seg = s & 31;
                *(uint4*)((u16*)Yv + (r0 + hh * 64 + row) * 256 + seg * 8) =
                    *(const uint4*)(smem + row * 264 + seg * 8);
            }
        }
    }
}

template<int XBF, int OUTF32>
__global__ __launch_bounds__(256, 2) void k_gemm_m(const void* __restrict__ Xv,
                                                   const u16* __restrict__ Wb,
                                                   const float* __restrict__ bias,
                                                   void* __restrict__ Yv)
{
    __shared__ __align__(16) u16 smem[26624];
    gemm_body<XBF, OUTF32>(Xv, Wb, bias, Yv, blockIdx.x, smem);
}

// Fused 3-projection GEMM: blockIdx.y selects {q,k,v}; Wb = pre-converted bf16.
__global__ __launch_bounds__(256, 2) void k_gemm_qkv(
    const float* __restrict__ X0, const float* __restrict__ X1, const float* __restrict__ X2,
    const u16* __restrict__ Wb,
    const float* __restrict__ b0, const float* __restrict__ b1, const float* __restrict__ b2,
    u16* __restrict__ Y0, u16* __restrict__ Y1, u16* __restrict__ Y2)
{
    __shared__ __align__(16) u16 smem[26624];
    const int sel = blockIdx.y;
    const float* X = sel == 0 ? X0 : sel == 1 ? X1 : X2;
    const float* bb = sel == 0 ? b0 : sel == 1 ? b1 : b2;
    u16* Y = sel == 0 ? Y0 : sel == 1 ? Y1 : Y2;
    gemm_body<0, 0>(X, Wb + sel * 65536, bb, Y, blockIdx.x, smem);
}

// ---------------- temporal attention (MFMA): one block per (t-pair, b) --------
__global__ __launch_bounds__(256) void k_attn_t(
    const u16* __restrict__ Qt, const u16* __restrict__ Kt, const u16* __restrict__ Vt,
    const u16* __restrict__ Ks, const u16* __restrict__ Vs,
    const int* __restrict__ maskT, const int* __restrict__ maskS,
    float* __restrict__ tw, u16* __restrict__ qkvt)
{
    const int tp = blockIdx.x, b = blockIdx.y;
    const int t0 = tp * 2;
    __shared__ __align__(16) u16 sQ [4 * 2 * 16 * 32];   // [h][ks][row16][32]
    __shared__ __align__(16) u16 sKT[4 * 2 * 16 * 32];
    __shared__ __align__(16) u16 sKS[4 * 2 * 32 * 32];
    __shared__ __align__(16) u16 sVT[4 * 64 * 72];       // [h][d64][key72], keys48-63=0
    __shared__ __align__(16) u16 sP [4 * 16 * 72];
    __shared__ int smT[2][8];
    __shared__ int smS[32];
    const int tid = threadIdx.x;

#pragma unroll
    for (int i = 0; i < 2; ++i) {
        const int fl = tid + i * 256;
        const int r = fl >> 5, c32 = fl & 31;
        const int h = c32 >> 3, ks = (c32 >> 2) & 1, seg = c32 & 3;
        const size_t src = (((size_t)b * T_ + t0 + (r >> 3)) * 8 + (r & 7)) * 256 + c32 * 8;
        const int dst = h * 1024 + ks * 512 + r * 32 + seg * 8;
        *(uint4*)(sQ  + dst) = *(const uint4*)(Qt + src);
        *(uint4*)(sKT + dst) = *(const uint4*)(Kt + src);
    }
#pragma unroll
    for (int i = 0; i < 4; ++i) {
        const int fl = tid + i * 256;
        const int r = fl >> 5, c32 = fl & 31;
        const int h = c32 >> 3, ks = (c32 >> 2) & 1, seg = c32 & 3;
        *(uint4*)(sKS + h * 2048 + ks * 1024 + r * 32 + seg * 8) =
            *(const uint4*)(Ks + ((size_t)b * S_ + r) * 256 + c32 * 8);
    }
    {
        const int key = tid & 63, dg = tid >> 6;
        const u16* vrow = nullptr;
        if (key < 16)      vrow = Vt + (((size_t)b * T_ + t0 + (key >> 3)) * 8 + (key & 7)) * 256;
        else if (key < 48) vrow = Vs + ((size_t)b * S_ + (key - 16)) * 256;
#pragma unroll
        for (int i = 0; i < 8; ++i) {
            const int dseg = dg * 8 + i;
            uint4 v = {0, 0, 0, 0};
            if (vrow) v = *(const uint4*)(vrow + dseg * 8);
            const int h = dseg >> 3, dl0 = (dseg & 7) * 8;
            const u16* pv = (const u16*)&v;
#pragma unroll
            for (int j = 0; j < 8; ++j)
                sVT[h * 4608 + (dl0 + j) * 72 + key] = pv[j];
        }
    }
    if (tid < 16) smT[tid >> 3][tid & 7] =
        maskT[((size_t)b * T_ + t0 + (tid >> 3)) * 8 + (tid & 7)];
    if (tid < 32) smS[tid] = maskS[b * S_ + tid];
    __syncthreads();

    const int h = tid >> 6, lane = tid & 63;
    const int c = lane & 15, g = lane >> 4, th = g >> 1;

    f32x4 at = {0,0,0,0}, as0 = {0,0,0,0}, as1 = {0,0,0,0};
#pragma unroll
    for (int ks = 0; ks < 2; ++ks) {
        bf16x8 aq = *(const bf16x8*)(sQ  + h * 1024 + ks * 512 + c * 32 + g * 8);
        bf16x8 bt = *(const bf16x8*)(sKT + h * 1024 + ks * 512 + c * 32 + g * 8);
        bf16x8 b0 = *(const bf16x8*)(sKS + h * 2048 + ks * 1024 + c * 32 + g * 8);
        bf16x8 b1 = *(const bf16x8*)(sKS + h * 2048 + ks * 1024 + 512 + c * 32 + g * 8);
        at  = __builtin_amdgcn_mfma_f32_16x16x32_bf16(aq, bt, at, 0, 0, 0);
        as0 = __builtin_amdgcn_mfma_f32_16x16x32_bf16(aq, b0, as0, 0, 0, 0);
        as1 = __builtin_amdgcn_mfma_f32_16x16x32_bf16(aq, b1, as1, 0, 0, 0);
    }

    const int vt = ((c >> 3) == th) ? smT[th][c & 7] : 0;
    const int v0 = smS[c], v1 = smS[16 + c];
    float st[4], s0[4], s1[4], mx[4];
#pragma unroll
    for (int r = 0; r < 4; ++r) {
        st[r] = vt ? at[r]  * 0.125f : -1e30f;
        s0[r] = v0 ? as0[r] * 0.125f : -1e30f;
        s1[r] = v1 ? as1[r] * 0.125f : -1e30f;
        mx[r] = fmaxf(fmaxf(st[r], s0[r]), s1[r]);
    }
#pragma unroll
    for (int o = 1; o < 16; o <<= 1)
#pragma unroll
        for (int r = 0; r < 4; ++r) mx[r] = fmaxf(mx[r], __shfl_xor(mx[r], o));
    float pt[4], p0[4], p1[4], sum[4];
#pragma unroll
    for (int r = 0; r < 4; ++r) {
        pt[r] = __expf(st[r] - mx[r]);
        p0[r] = __expf(s0[r] - mx[r]);
        p1[r] = __expf(s1[r] - mx[r]);
        sum[r] = pt[r] + p0[r] + p1[r];
    }
#pragma unroll
    for (int o = 1; o < 16; o <<= 1)
#pragma unroll
        for (int r = 0; r < 4; ++r) sum[r] += __shfl_xor(sum[r], o);
#pragma unroll
    for (int r = 0; r < 4; ++r) {
        const float inv = 1.0f / sum[r];
        pt[r] *= inv; p0[r] *= inv; p1[r] *= inv;
    }

#pragma unroll
    for (int r = 0; r < 4; ++r) {
        const int row = g * 4 + r;
        const int tt = t0 + (row >> 3), m = row & 7;
        float* twp = tw + ((((size_t)b * H_ + h) * T_ + tt) * 8 + m) * NKT;
        if ((c >> 3) == th) twp[c & 7] = pt[r];
        twp[8 + c]  = p0[r];
        twp[24 + c] = p1[r];
        u16* sp = sP + h * 1152 + row * 72;
        sp[c]      = f2b(pt[r]);
        sp[16 + c] = f2b(p0[r]);
        sp[32 + c] = f2b(p1[r]);
        sp[48 + c] = 0;
    }

    f32x4 o4[4] = {{0,0,0,0}, {0,0,0,0}, {0,0,0,0}, {0,0,0,0}};
#pragma unroll
    for (int ks = 0; ks < 2; ++ks) {
        bf16x8 pa = *(const bf16x8*)(sP + h * 1152 + c * 72 + ks * 32 + g * 8);
#pragma unroll
        for (int dt = 0; dt < 4; ++dt) {
            bf16x8 pb = *(const bf16x8*)(sVT + h * 4608 + (dt * 16 + c) * 72 + ks * 32 + g * 8);
            o4[dt] = __builtin_amdgcn_mfma_f32_16x16x32_bf16(pa, pb, o4[dt], 0, 0, 0);
        }
    }
#pragma unroll
    for (int dt = 0; dt < 4; ++dt)
#pragma unroll
        for (int r = 0; r < 4; ++r) {
            const int row = g * 4 + r;
            const int tt = t0 + (row >> 3), m = row & 7;
            qkvt[(((size_t)b * T_ + tt) * 8 + m) * 256 + h * 64 + dt * 16 + c] = f2b(o4[dt][r]);
        }
}

// ---------------- static branch: raw masked scores (MFMA) ----------------
__global__ __launch_bounds__(256) void k_attn_s_scores(
    const u16* __restrict__ Qs, const u16* __restrict__ Kt, const u16* __restrict__ Ks,
    const int* __restrict__ maskT, const int* __restrict__ maskS,
    float* __restrict__ raw)
{
    const int ch = blockIdx.x, h = blockIdx.y, b = blockIdx.z;
    const int nk = (ch < 32) ? 128 : 32;
    const int k0 = ch * 128;
    __shared__ __align__(16) u16 sQ[2 * 32 * 32];
    __shared__ __align__(16) u16 sK[2 * 128 * 32];
    __shared__ int sM[128];
    const int tid = threadIdx.x;

    {   const int q = tid >> 3, c8 = tid & 7;
        const int ks = c8 >> 2, seg = c8 & 3;
        *(uint4*)(sQ + ks * 1024 + q * 32 + seg * 8) =
            *(const uint4*)(Qs + ((size_t)b * S_ + q) * 256 + h * 64 + c8 * 8);
    }
#pragma unroll
    for (int i = 0; i < 4; ++i) {
        const int fl = tid + i * 256;
        const int key = fl >> 3, c8 = fl & 7;
        const int ks = c8 >> 2, seg = c8 & 3;
        if (key < nk) {
            const u16* src = (ch < 32)
                ? (Kt + ((size_t)b * TM_ + k0 + key) * 256 + h * 64 + c8 * 8)
                : (Ks + ((size_t)b * S_  +      key) * 256 + h * 64 + c8 * 8);
            *(uint4*)(sK + ks * 4096 + key * 32 + seg * 8) = *(const uint4*)src;
        }
    }
    if (tid < nk) sM[tid] = (ch < 32) ? maskT[(size_t)b * TM_ + k0 + tid]
                                      : maskS[b * S_ + tid];
    __syncthreads();

    const int w = tid >> 6, lane = tid & 63;
    if (w * 32 >= nk) return;
    const int c = lane & 15, g = lane >> 4;

    f32x4 acc[2][2] = {{{0,0,0,0}, {0,0,0,0}}, {{0,0,0,0}, {0,0,0,0}}};
#pragma unroll
    for (int ks = 0; ks < 2; ++ks) {
        bf16x8 a0 = *(const bf16x8*)(sQ + ks * 1024 +        c * 32 + g * 8);
        bf16x8 a1 = *(const bf16x8*)(sQ + ks * 1024 + 512 +  c * 32 + g * 8);
        bf16x8 b0 = *(const bf16x8*)(sK + ks * 4096 + (w * 32 +      c) * 32 + g * 8);
        bf16x8 b1 = *(const bf16x8*)(sK + ks * 4096 + (w * 32 + 16 + c) * 32 + g * 8);
        acc[0][0] = __builtin_amdgcn_mfma_f32_16x16x32_bf16(a0, b0, acc[0][0], 0, 0, 0);
        acc[0][1] = __builtin_amdgcn_mfma_f32_16x16x32_bf16(a0, b1, acc[0][1], 0, 0, 0);
        acc[1][0] = __builtin_amdgcn_mfma_f32_16x16x32_bf16(a1, b0, acc[1][0], 0, 0, 0);
        acc[1][1] = __builtin_amdgcn_mfma_f32_16x16x32_bf16(a1, b1, acc[1][1], 0, 0, 0);
    }
#pragma unroll
    for (int rt = 0; rt < 2; ++rt)
#pragma unroll
        for (int ct = 0; ct < 2; ++ct) {
            const int kl = w * 32 + ct * 16 + c;
            const float madd = sM[kl] ? 0.f : -1e30f;
#pragma unroll
            for (int r = 0; r < 4; ++r) {
                const int q = rt * 16 + g * 4 + r;
                raw[(((size_t)b * H_ + h) * S_ + q) * NKS + k0 + kl] =
                    acc[rt][ct][r] * 0.125f + madd;
            }
        }
}

// ---------------- static branch: row softmax (reads raw, writes sw only) -------
__global__ __launch_bounds__(256) void k_attn_s_softmax(
    const float* __restrict__ raw, float* __restrict__ sw)
{
    const int q = blockIdx.x, h = blockIdx.y, b = blockIdx.z;
    __shared__ float sRow[NKS];
    __shared__ float red[8];
    const int tid = threadIdx.x;
    const size_t base = (((size_t)b * H_ + h) * S_ + q) * NKS;

    float mx = -1e30f;
    for (int i = tid; i < NKS; i += 256) {
        const float v = raw[base + i];
        sRow[i] = v;
        mx = fmaxf(mx, v);
    }
    for (int o = 32; o; o >>= 1) mx = fmaxf(mx, __shfl_xor(mx, o));
    if ((tid & 63) == 0) red[tid >> 6] = mx;
    __syncthreads();
    mx = fmaxf(fmaxf(red[0], red[1]), fmaxf(red[2], red[3]));

    float sum = 0.f;
    for (int i = tid; i < NKS; i += 256) {
        const float e = __expf(sRow[i] - mx);
        sRow[i] = e;
        sum += e;
    }
    for (int o = 32; o; o >>= 1) sum += __shfl_xor(sum, o);
    if ((tid & 63) == 0) red[4 + (tid >> 6)] = sum;
    __syncthreads();
    sum = (red[4] + red[5]) + (red[6] + red[7]);
    const float inv = 1.0f / sum;

    for (int i = tid; i < NKS; i += 256)
        sw[base + i] = sRow[i] * inv;           // single copy; pv reads sw
}

// ---------------- static branch: split-K PV partials (reads sw) ----------------
__global__ __launch_bounds__(256) void k_attn_s_pv_part(
    const float* __restrict__ w, const u16* __restrict__ Vt, const u16* __restrict__ Vs,
    float* __restrict__ part)
{
    const int ch = blockIdx.x, h = blockIdx.y, b = blockIdx.z;
    const int nk = (ch < 32) ? 128 : 32;
    const int k0 = ch * 128;
    __shared__ float sW[32][132];
    __shared__ __align__(16) u16 sV[128 * 64];
    const int tid = threadIdx.x;

#pragma unroll
    for (int i = 0; i < 4; ++i) {
        const int fl = tid + i * 256;
        const int q = fl >> 5, k4 = fl & 31;
        if (k4 * 4 < nk)
            *(float4*)&sW[q][k4 * 4] =
                *(const float4*)(w + (((size_t)b * H_ + h) * S_ + q) * NKS + k0 + k4 * 4);
    }
#pragma unroll
    for (int i = 0; i < 4; ++i) {
        const int fl = tid + i * 256;
        const int key = fl >> 3, pp = fl & 7;
        if (key < nk) {
            const u16* src = (ch < 32)
                ? (Vt + ((size_t)b * TM_ + k0 + key) * D_ + h * HD_ + pp * 8)
                : (Vs + ((size_t)b * S_  +      key) * D_ + h * HD_ + pp * 8);
            ((uint4*)sV)[fl] = *(const uint4*)src;
        }
    }
    __syncthreads();

    const int d = tid & 63, qg = tid >> 6;
    float acc[8] = {0,0,0,0,0,0,0,0};
    for (int kk = 0; kk < nk; kk += 4) {
        const float v0 = b2f(sV[(kk + 0) * 64 + d]);
        const float v1 = b2f(sV[(kk + 1) * 64 + d]);
        const float v2 = b2f(sV[(kk + 2) * 64 + d]);
        const float v3 = b2f(sV[(kk + 3) * 64 + d]);
#pragma unroll
        for (int j = 0; j < 8; ++j) {
            const float4 wv = *(const float4*)&sW[qg * 8 + j][kk];
            acc[j] += wv.x * v0 + wv.y * v1 + wv.z * v2 + wv.w * v3;
        }
    }

    float* pb = part + (((size_t)ch * B_ + b) * H_ + h) * 2048;
#pragma unroll
    for (int j = 0; j < 8; ++j)
        pb[(qg * 8 + j) * 64 + d] = acc[j];
}

// ---------------- static branch: PV reduce ----------------
__global__ __launch_bounds__(256) void k_attn_s_pv_red(
    const float* __restrict__ part, u16* __restrict__ qkvs)
{
    const int h = blockIdx.x, b = blockIdx.y;
    const int tid = threadIdx.x;
    for (int i = tid; i < 2048; i += 256) {
        float s = 0.f;
#pragma unroll
        for (int c = 0; c < 33; ++c)
            s += part[(((size_t)c * B_ + b) * H_ + h) * 2048 + i];
        const int q = i >> 6, d = i & 63;
        qkvs[((size_t)b * S_ + q) * D_ + h * HD_ + d] = f2b(s);
    }
}

// ---------------- launch ----------------
extern "C" void kernel_launch(void* const* d_in, const int* in_sizes, int n_in,
                              void* d_out, int out_size, void* d_ws, size_t ws_size,
                              hipStream_t stream)
{
    const float* q_t = (const float*)d_in[0];
    const float* q_s = (const float*)d_in[1];
    const float* k_t = (const float*)d_in[2];
    const float* v_t = (const float*)d_in[3];
    const float* k_s = (const float*)d_in[4];
    const float* v_s = (const float*)d_in[5];
    const float* q_w = (const float*)d_in[6];
    const float* q_b = (const float*)d_in[7];
    const float* k_w = (const float*)d_in[8];
    const float* k_b = (const float*)d_in[9];
    const float* v_w = (const float*)d_in[10];
    const float* v_b = (const float*)d_in[11];
    const float* o_w = (const float*)d_in[12];
    const float* o_b = (const float*)d_in[13];
    const int* maskT = (const int*)d_in[14];
    // d_in[15] = mask_fcst: unused by the reference
    const int* maskS = (const int*)d_in[16];
    float* out = (float*)d_out;

    char* ws = (char*)d_ws;
    u16*   Kt   = (u16*)(ws + 0);
    u16*   Vt   = (u16*)(ws + 33554432);
    u16*   QKVt = (u16*)(ws + 67108864);
    float* part = (float*)(ws + 67108864);   // aliases QKVt (dead after out_t GEMM)
    u16*   Wqkv = (u16*)(ws + 67108864);     // aliases QKVt: live only during qkv GEMMs
    u16*   Qs   = (u16*)(ws + 100663296);
    u16*   Ks   = (u16*)(ws + 100925440);
    u16*   Vs   = (u16*)(ws + 101187584);
    u16*   QKVs = (u16*)(ws + 101449728);
    u16*   Qt   = (u16*)(ws + 101711872);
    float* raw  = (float*)(ws + 101711872);  // aliases Qt (dead before scores run)
    u16*   Wo   = (u16*)(ws + 101711872);    // aliases raw head: converted twice (see order)
    if (ws_size < 135528448) return;         // required workspace

    float* out_t = out;                 // [B,T,M,D]
    float* out_s = out + 16777216;      // [B,S,D]
    float* tw    = out + 16908288;      // [B,H,T,M,40]
    float* sw    = out + 27394048;      // [B,H,S,4128]

    const dim3 blk(256);
    // W pre-convert (q,k,v) into dead QKVt region
    k_cvt_w<<<dim3(32, 3), blk, 0, stream>>>(q_w, k_w, v_w, Wqkv);

    k_gemm_qkv<<<dim3(512, 3), blk, 0, stream>>>(q_t, k_t, v_t, Wqkv,
                                                 q_b, k_b, v_b, Qt, Kt, Vt);
    k_gemm_qkv<<<dim3(4, 3),   blk, 0, stream>>>(q_s, k_s, v_s, Wqkv,
                                                 q_b, k_b, v_b, Qs, Ks, Vs);

    k_attn_t<<<dim3(256, 16), blk, 0, stream>>>(Qt, Kt, Vt, Ks, Vs, maskT, maskS, tw, QKVt);

    // o_w convert #1 into raw region (Qt dead after attn_t; scores clobbers it later)
    k_cvt_w<<<dim3(32, 1), blk, 0, stream>>>(o_w, o_w, o_w, Wo);
    // out_t projection: frees QKVt so PV partials can alias it.
    k_gemm_m<1,1><<<dim3(512), blk, 0, stream>>>(QKVt, Wo, o_b, out_t);

    k_attn_s_scores<<<dim3(33, 4, 16), blk, 0, stream>>>(Qs, Kt, Ks, maskT, maskS, raw);
    k_attn_s_softmax<<<dim3(32, 4, 16), blk, 0, stream>>>(raw, sw);
    // o_w convert #2 (raw dead after softmax; pv reads sw)
    k_cvt_w<<<dim3(32, 1), blk, 0, stream>>>(o_w, o_w, o_w, Wo);
    k_attn_s_pv_part<<<dim3(33, 4, 16), blk, 0, stream>>>(sw, Vt, Vs, part);
    k_attn_s_pv_red<<<dim3(4, 16), blk, 0, stream>>>(part, QKVs);

    k_gemm_m<1,1><<<dim3(4),   blk, 0, stream>>>(QKVs, Wo, o_b, out_s);
}